// Round 3
// baseline (664.148 us; speedup 1.0000x reference)
//
#include <hip/hip_runtime.h>
#include <math.h>

typedef unsigned short u16;
typedef __bf16 bf16;
typedef bf16 bf16x8 __attribute__((ext_vector_type(8)));
typedef float f32x4 __attribute__((ext_vector_type(4)));

#define DEV __device__ __forceinline__
#define FENCE() asm volatile("" ::: "memory")
#define LGKM0() asm volatile("s_waitcnt lgkmcnt(0)" ::: "memory")
#define VMW(n) asm volatile("s_waitcnt vmcnt(" #n ")" ::: "memory")
#define SB0() __builtin_amdgcn_sched_barrier(0)
#define MFMA(a, b, c) __builtin_amdgcn_mfma_f32_16x16x32_bf16(a, b, c, 0, 0, 0)

DEV u16 f2b(float f) {
  unsigned u = __builtin_bit_cast(unsigned, f);
  u += 0x7fffu + ((u >> 16) & 1u);
  return (u16)(u >> 16);
}
DEV float b2f(u16 h) {
  unsigned u = ((unsigned)h) << 16;
  return __builtin_bit_cast(float, u);
}
DEV float gelu_f(float x) { return 0.5f * x * (1.0f + erff(x * 0.70710678118654752f)); }

DEV void gl2lds16(const void* g, void* l) {
  __builtin_amdgcn_global_load_lds(
      (const __attribute__((address_space(1))) unsigned int*)g,
      (__attribute__((address_space(3))) unsigned int*)l, 16, 0, 0);
}

// ---------------- weight transpose + fp32->bf16 ----------------
__global__ void k_transpose_cvt(const float* __restrict__ src, u16* __restrict__ dst,
                                int R, int C) {
  __shared__ float tile[32][33];
  const int c0 = blockIdx.x * 32, r0 = blockIdx.y * 32;
  const int tx = threadIdx.x, ty = threadIdx.y;  // 32 x 8
#pragma unroll
  for (int i = 0; i < 32; i += 8)
    tile[ty + i][tx] = src[(long)(r0 + ty + i) * C + c0 + tx];
  __syncthreads();
#pragma unroll
  for (int i = 0; i < 32; i += 8)
    dst[(long)(c0 + ty + i) * R + r0 + tx] = f2b(tile[tx][ty + i]);
}

// ---------------- FiLM ss = cond @ fw + fb, split-K ----------------
__global__ __launch_bounds__(256) void k_film_part(const float* __restrict__ cond,
                                                   const float* __restrict__ fw,
                                                   float* __restrict__ part) {
  const int j = blockIdx.x * 256 + threadIdx.x;
  const int b = blockIdx.y;
  const int kz = blockIdx.z;
  const float* cp = cond + b * 1024 + kz * 128;
  const float* wp = fw + (long)kz * 128 * 2048 + j;
  float acc = 0.0f;
#pragma unroll 4
  for (int d = 0; d < 128; ++d) acc = fmaf(cp[d], wp[(long)d * 2048], acc);
  part[((kz * 4 + b) << 11) + j] = acc;
}
__global__ __launch_bounds__(256) void k_film_comb(const float* __restrict__ part,
                                                   const float* __restrict__ fb,
                                                   float* __restrict__ ss) {
  const int j = blockIdx.x * 256 + threadIdx.x;
  const int b = blockIdx.y;
  float a = fb[j];
#pragma unroll
  for (int kz = 0; kz < 8; ++kz) a += part[((kz * 4 + b) << 11) + j];
  ss[b * 2048 + j] = a;
}

// ---------------- fused RMSNorm + FiLM, fp32 in -> bf16 out ----------------
__global__ __launch_bounds__(256) void k_rmsfilm(const float* __restrict__ x,
                                                 const float* __restrict__ nw,
                                                 const float* __restrict__ ss,
                                                 u16* __restrict__ h) {
  const int row = blockIdx.x;
  const int b = row >> 11;
  const int t = threadIdx.x;
  const float4 v = ((const float4*)(x + (long)row * 1024))[t];
  float s = v.x * v.x + v.y * v.y + v.z * v.z + v.w * v.w;
#pragma unroll
  for (int off = 32; off; off >>= 1) s += __shfl_xor(s, off);
  __shared__ float red[4];
  const int wv = t >> 6, lane = t & 63;
  if (lane == 0) red[wv] = s;
  __syncthreads();
  const float tot = red[0] + red[1] + red[2] + red[3];
  const float rn = rsqrtf(tot * (1.0f / 1024.0f) + 1e-6f);
  const float4 w4 = ((const float4*)nw)[t];
  const float4 sc = ((const float4*)(ss + b * 2048))[t];
  const float4 sh = ((const float4*)(ss + b * 2048 + 1024))[t];
  ushort4 o;
  o.x = f2b(v.x * rn * w4.x * (1.0f + sc.x) + sh.x);
  o.y = f2b(v.y * rn * w4.y * (1.0f + sc.y) + sh.y);
  o.z = f2b(v.z * rn * w4.z * (1.0f + sc.z) + sh.z);
  o.w = f2b(v.w * rn * w4.w * (1.0f + sc.w) + sh.w);
  ((ushort4*)(h + (long)row * 1024))[t] = o;
}

// ---------------- row softmax over 2048 bf16, in place ----------------
__global__ __launch_bounds__(256) void k_softmax(u16* __restrict__ S) {
  u16* p = S + ((long)blockIdx.x << 11);
  const int t = threadIdx.x;
  ushort4 u0 = ((ushort4*)p)[2 * t], u1 = ((ushort4*)p)[2 * t + 1];
  float f[8] = {b2f(u0.x), b2f(u0.y), b2f(u0.z), b2f(u0.w),
                b2f(u1.x), b2f(u1.y), b2f(u1.z), b2f(u1.w)};
  float m = f[0];
#pragma unroll
  for (int i = 1; i < 8; ++i) m = fmaxf(m, f[i]);
#pragma unroll
  for (int off = 32; off; off >>= 1) m = fmaxf(m, __shfl_xor(m, off));
  __shared__ float red[4];
  const int wv = t >> 6, lane = t & 63;
  if (lane == 0) red[wv] = m;
  __syncthreads();
  m = fmaxf(fmaxf(red[0], red[1]), fmaxf(red[2], red[3]));
  float s = 0.0f;
#pragma unroll
  for (int i = 0; i < 8; ++i) {
    f[i] = __expf(f[i] - m);
    s += f[i];
  }
#pragma unroll
  for (int off = 32; off; off >>= 1) s += __shfl_xor(s, off);
  __syncthreads();
  if (lane == 0) red[wv] = s;
  __syncthreads();
  const float inv = 1.0f / (red[0] + red[1] + red[2] + red[3]);
  ushort4 o0, o1;
  o0.x = f2b(f[0] * inv); o0.y = f2b(f[1] * inv);
  o0.z = f2b(f[2] * inv); o0.w = f2b(f[3] * inv);
  o1.x = f2b(f[4] * inv); o1.y = f2b(f[5] * inv);
  o1.z = f2b(f[6] * inv); o1.w = f2b(f[7] * inv);
  ((ushort4*)p)[2 * t] = o0;
  ((ushort4*)p)[2 * t + 1] = o1;
}

// ---------------- m201-style 8-wave pipelined bf16 MFMA GEMM ----------------
// C = A[M,K] @ Bt[N,K]^T. BM=256 fixed; BN=256 (2x4 waves) or 128 (4x2 waves).
// K-tile = 64 = two 32-k-halves, each stored [rows][32] bf16 (64B rows) in LDS,
// XOR-swizzled (col16 ^= (row>>1)&3) on both write-source and read side.
// Per K-tile: 4 phases (BIG) / 2 phases (SMALL), 16 MFMA each; one half-tile
// staged per phase into the region freed in the previous phase; counted vmcnt
// once per K-tile (never 0 in steady state). Requires K >= 128, K % 64 == 0.
enum { EB = 1, ES = 2, EG = 4, ER = 8, EQKV = 16 };

template <int BN, int EPI, typename OutT>
__global__ __launch_bounds__(512, 2) void k_gemm(
    const u16* __restrict__ A, const u16* __restrict__ B, OutT* __restrict__ C,
    const float* __restrict__ bias, const float* __restrict__ bias2,
    const float* __restrict__ bias3, const float* __restrict__ resid,
    u16* __restrict__ Vt, float scale, int N, int K, long sAb, long sBb, long sCb) {
  constexpr bool BIG = (BN == 256);
  constexpr int WR = BIG ? 128 : 64;  // rows per wave
  constexpr int MR = WR / 16;         // 8 or 4
  constexpr int A_KH = 8192;          // u16 per A k-half (256x32)
  constexpr int B_KH = BN * 32;       // u16 per B k-half
  constexpr int DBUF = 2 * A_KH + 2 * B_KH;
  constexpr int NBJ = BN / 128;
  __shared__ u16 sm[2 * DBUF];

  const int tid = threadIdx.x, lane = tid & 63, wid = tid >> 6;
  const int r = lane & 15, q = lane >> 4;
  const int wm = BIG ? (wid >> 2) : (wid >> 1);
  const int wn = BIG ? (wid & 3) : (wid & 1);
  const int cswz = (q ^ ((r >> 1) & 3)) * 8;
  const int arow = wm * WR + r;
  const int brow = wn * 64 + r;
  const int srow = tid >> 2;
  const int scol = ((tid & 3) ^ ((tid >> 3) & 3)) * 8;
  const int sdst = tid * 8;

  // XCD-aware swizzle (all launches have gridDim.x*gridDim.y % 8 == 0)
  int flat = blockIdx.y * gridDim.x + blockIdx.x;
  const int nxy = gridDim.x * gridDim.y;
  flat = (flat & 7) * (nxy >> 3) + (flat >> 3);
  const int bx = flat % gridDim.x, by = flat / gridDim.x;

  const long bm = (long)by * 256, bn = (long)bx * BN;
  const u16* Ab = A + (long)blockIdx.z * sAb + bm * K;
  const u16* Bb = B + (long)blockIdx.z * sBb + bn * K;

  f32x4 acc[MR][4] = {};
  const int NT = K >> 6;

  auto stA = [&](int buf, int kh, int t) {
    const long gk = (long)t * 64 + kh * 32;
#pragma unroll
    for (int j = 0; j < 2; ++j)
      gl2lds16(Ab + (long)(j * 128 + srow) * K + gk + scol,
               &sm[buf * DBUF + kh * A_KH + j * 4096 + sdst]);
  };
  auto stB = [&](int buf, int kh, int t) {
    const long gk = (long)t * 64 + kh * 32;
#pragma unroll
    for (int j = 0; j < NBJ; ++j)
      gl2lds16(Bb + (long)(j * 128 + srow) * K + gk + scol,
               &sm[buf * DBUF + 2 * A_KH + kh * B_KH + j * 4096 + sdst]);
  };
  auto ldA = [&](int buf, int kh, int mi) {
    return *(const bf16x8*)&sm[buf * DBUF + kh * A_KH + (arow + mi * 16) * 32 + cswz];
  };
  auto ldB = [&](int buf, int kh, int ni) {
    return *(const bf16x8*)&sm[buf * DBUF + 2 * A_KH + kh * B_KH + (brow + ni * 16) * 32 + cswz];
  };

  // prologue: tile0 fully + tile1 minus its last B/AB half(s)
  stA(0, 0, 0); stB(0, 0, 0); stA(0, 1, 0); stB(0, 1, 0);
  if constexpr (BIG) {
    if (NT > 1) { stA(1, 0, 1); stB(1, 0, 1); stA(1, 1, 1); }
    VMW(6);
  } else {
    if (NT > 1) { stA(1, 0, 1); stB(1, 0, 1); }
    VMW(3);
  }
  FENCE(); __builtin_amdgcn_s_barrier(); FENCE();

  for (int t = 0; t < NT; ++t) {
    const int X = t & 1, Y = X ^ 1;
    const bool p1 = (t + 1) < NT, p2 = (t + 2) < NT;
    if constexpr (BIG) {
      bf16x8 a[8], bb[2];
      // ---- P1: kh0, ni 0-1 ; stage (t+1).Bkh1 -> Y ----
#pragma unroll
      for (int mi = 0; mi < 8; ++mi) a[mi] = ldA(X, 0, mi);
      bb[0] = ldB(X, 0, 0); bb[1] = ldB(X, 0, 1);
      if (p1) stB(Y, 1, t + 1);
      FENCE(); __builtin_amdgcn_s_barrier();
      LGKM0(); SB0(); __builtin_amdgcn_s_setprio(1);
#pragma unroll
      for (int mi = 0; mi < 8; ++mi) {
        acc[mi][0] = MFMA(a[mi], bb[0], acc[mi][0]);
        acc[mi][1] = MFMA(a[mi], bb[1], acc[mi][1]);
      }
      __builtin_amdgcn_s_setprio(0); FENCE(); __builtin_amdgcn_s_barrier(); FENCE();
      // ---- P2: kh0, ni 2-3 ; stage (t+2).Akh0 -> X ----
      bb[0] = ldB(X, 0, 2); bb[1] = ldB(X, 0, 3);
      if (p2) stA(X, 0, t + 2);
      FENCE(); __builtin_amdgcn_s_barrier();
      LGKM0(); SB0(); __builtin_amdgcn_s_setprio(1);
#pragma unroll
      for (int mi = 0; mi < 8; ++mi) {
        acc[mi][2] = MFMA(a[mi], bb[0], acc[mi][2]);
        acc[mi][3] = MFMA(a[mi], bb[1], acc[mi][3]);
      }
      __builtin_amdgcn_s_setprio(0); FENCE(); __builtin_amdgcn_s_barrier(); FENCE();
      // ---- P3: kh1, ni 0-1 ; stage (t+2).Bkh0 -> X ----
#pragma unroll
      for (int mi = 0; mi < 8; ++mi) a[mi] = ldA(X, 1, mi);
      bb[0] = ldB(X, 1, 0); bb[1] = ldB(X, 1, 1);
      if (p2) stB(X, 0, t + 2);
      FENCE(); __builtin_amdgcn_s_barrier();
      LGKM0(); SB0(); __builtin_amdgcn_s_setprio(1);
#pragma unroll
      for (int mi = 0; mi < 8; ++mi) {
        acc[mi][0] = MFMA(a[mi], bb[0], acc[mi][0]);
        acc[mi][1] = MFMA(a[mi], bb[1], acc[mi][1]);
      }
      __builtin_amdgcn_s_setprio(0); FENCE(); __builtin_amdgcn_s_barrier(); FENCE();
      // ---- P4: kh1, ni 2-3 ; stage (t+2).Akh1 -> X ; counted wait ----
      bb[0] = ldB(X, 1, 2); bb[1] = ldB(X, 1, 3);
      if (p2) stA(X, 1, t + 2);
      FENCE(); __builtin_amdgcn_s_barrier();
      LGKM0(); SB0(); __builtin_amdgcn_s_setprio(1);
#pragma unroll
      for (int mi = 0; mi < 8; ++mi) {
        acc[mi][2] = MFMA(a[mi], bb[0], acc[mi][2]);
        acc[mi][3] = MFMA(a[mi], bb[1], acc[mi][3]);
      }
      __builtin_amdgcn_s_setprio(0); FENCE();
      if (p1) { if (p2) { VMW(6); } else { VMW(0); } }
      __builtin_amdgcn_s_barrier(); FENCE();
    } else {
      bf16x8 a[4], b[4];
      // ---- P1: kh0 ; stage (t+1).{Akh1,Bkh1} -> Y ----
#pragma unroll
      for (int mi = 0; mi < 4; ++mi) a[mi] = ldA(X, 0, mi);
#pragma unroll
      for (int ni = 0; ni < 4; ++ni) b[ni] = ldB(X, 0, ni);
      if (p1) { stA(Y, 1, t + 1); stB(Y, 1, t + 1); }
      FENCE(); __builtin_amdgcn_s_barrier();
      LGKM0(); SB0(); __builtin_amdgcn_s_setprio(1);
#pragma unroll
      for (int mi = 0; mi < 4; ++mi)
#pragma unroll
        for (int ni = 0; ni < 4; ++ni)
          acc[mi][ni] = MFMA(a[mi], b[ni], acc[mi][ni]);
      __builtin_amdgcn_s_setprio(0); FENCE(); __builtin_amdgcn_s_barrier(); FENCE();
      // ---- P2: kh1 ; stage (t+2).{Akh0,Bkh0} -> X ; counted wait ----
#pragma unroll
      for (int mi = 0; mi < 4; ++mi) a[mi] = ldA(X, 1, mi);
#pragma unroll
      for (int ni = 0; ni < 4; ++ni) b[ni] = ldB(X, 1, ni);
      if (p2) { stA(X, 0, t + 2); stB(X, 0, t + 2); }
      FENCE(); __builtin_amdgcn_s_barrier();
      LGKM0(); SB0(); __builtin_amdgcn_s_setprio(1);
#pragma unroll
      for (int mi = 0; mi < 4; ++mi)
#pragma unroll
        for (int ni = 0; ni < 4; ++ni)
          acc[mi][ni] = MFMA(a[mi], b[ni], acc[mi][ni]);
      __builtin_amdgcn_s_setprio(0); FENCE();
      if (p1) { if (p2) { VMW(3); } else { VMW(0); } }
      __builtin_amdgcn_s_barrier(); FENCE();
    }
  }

  // ---------------- epilogue ----------------
  const long cb = (long)blockIdx.z * sCb;
#pragma unroll
  for (int ni = 0; ni < 4; ++ni) {
    const long col = bn + wn * 64 + ni * 16 + r;
    float bv = 0.0f;
    int reg = 0, c = (int)col;
    if constexpr ((EPI & EB) != 0) bv = bias[col];
    if constexpr ((EPI & EQKV) != 0) {
      reg = (int)(col >> 10);
      c = (int)col & 1023;
      bv = (reg == 0) ? bias[c] : (reg == 1) ? bias2[c] : bias3[c];
    }
#pragma unroll
    for (int mi = 0; mi < MR; ++mi) {
#pragma unroll
      for (int j = 0; j < 4; ++j) {
        const long row = bm + wm * WR + mi * 16 + q * 4 + j;
        float v = acc[mi][ni][j];
        if constexpr ((EPI & ES) != 0) v *= scale;
        if constexpr ((EPI & (EB | EQKV)) != 0) v += bv;
        if constexpr ((EPI & EG) != 0) v = gelu_f(v);
        if constexpr ((EPI & ER) != 0) v += resid[row * N + col];
        if constexpr ((EPI & EQKV) != 0) {
          if (reg < 2)
            ((u16*)C)[(long)reg * 8388608 + row * 1024 + c] = f2b(v);
          else
            Vt[((row >> 11) << 21) + ((long)c << 11) + (row & 2047)] = f2b(v);
        } else if constexpr (sizeof(OutT) == 4) {
          C[cb + row * N + col] = v;
        } else {
          C[cb + row * N + col] = f2b(v);
        }
      }
    }
  }
}

extern "C" void kernel_launch(void* const* d_in, const int* in_sizes, int n_in,
                              void* d_out, int out_size, void* d_ws, size_t ws_size,
                              hipStream_t stream) {
  const float* x    = (const float*)d_in[0];
  const float* cond = (const float*)d_in[1];
  const float* n1w  = (const float*)d_in[2];
  const float* f1w  = (const float*)d_in[3];
  const float* f1b  = (const float*)d_in[4];
  const float* qw   = (const float*)d_in[5];
  const float* qb   = (const float*)d_in[6];
  const float* kw   = (const float*)d_in[7];
  const float* kb   = (const float*)d_in[8];
  const float* vw   = (const float*)d_in[9];
  const float* vb   = (const float*)d_in[10];
  const float* pw   = (const float*)d_in[11];
  const float* pb   = (const float*)d_in[12];
  const float* n2w  = (const float*)d_in[13];
  const float* f2w  = (const float*)d_in[14];
  const float* f2b_ = (const float*)d_in[15];
  const float* w1   = (const float*)d_in[16];
  const float* b1   = (const float*)d_in[17];
  const float* w2   = (const float*)d_in[18];
  const float* b2   = (const float*)d_in[19];
  float* out = (float*)d_out;

  char* ws = (char*)d_ws;
  size_t o = 0;
  auto alloc = [&](size_t bytes) {
    size_t ret = o;
    o += (bytes + 255) & ~(size_t)255;
    return ret;
  };
  const long N = 2048, D = 1024, H = 4096;

  u16* qkvT = (u16*)(ws + alloc(3 * D * D * 2));  // [3072][1024] = qT;kT;vT
  u16* pT   = (u16*)(ws + alloc(D * D * 2));
  u16* w1T  = (u16*)(ws + alloc(D * H * 2));
  u16* w2T  = (u16*)(ws + alloc(D * H * 2));
  float* ss1  = (float*)(ws + alloc(4 * 2 * D * 4));
  float* ss2  = (float*)(ws + alloc(4 * 2 * D * 4));
  float* part = (float*)(ws + alloc(8 * 4 * 2 * D * 4));
  u16* h    = (u16*)(ws + alloc(4 * N * D * 2));    // 16 MB
  float* x1 = (float*)(ws + alloc(4 * N * D * 4));  // 32 MB
  u16* AO   = (u16*)(ws + alloc(4 * N * D * 2));    // 16 MB
  const size_t big = o;  // alias region
  u16* Q    = (u16*)(ws + alloc(4 * N * D * 2));    // Q and Kb must stay adjacent
  u16* Kb   = (u16*)(ws + alloc(4 * N * D * 2));
  u16* Vt   = (u16*)(ws + alloc(4 * N * D * 2));
  u16* S    = (u16*)(ws + alloc(4 * N * N * 2));    // 32 MB
  u16* h1   = (u16*)(ws + big);                     // 64 MB, aliases Q..S
  (void)ws_size; (void)in_sizes; (void)n_in; (void)out_size; (void)Kb;

  dim3 tb(32, 8);
  k_transpose_cvt<<<dim3(32, 32), tb, 0, stream>>>(qw, qkvT, 1024, 1024);
  k_transpose_cvt<<<dim3(32, 32), tb, 0, stream>>>(kw, qkvT + 1024 * 1024, 1024, 1024);
  k_transpose_cvt<<<dim3(32, 32), tb, 0, stream>>>(vw, qkvT + 2 * 1024 * 1024, 1024, 1024);
  k_transpose_cvt<<<dim3(32, 32), tb, 0, stream>>>(pw, pT, 1024, 1024);
  k_transpose_cvt<<<dim3(128, 32), tb, 0, stream>>>(w1, w1T, 1024, 4096);
  k_transpose_cvt<<<dim3(32, 128), tb, 0, stream>>>(w2, w2T, 4096, 1024);

  k_film_part<<<dim3(8, 4, 8), 256, 0, stream>>>(cond, f1w, part);
  k_film_comb<<<dim3(8, 4), 256, 0, stream>>>(part, f1b, ss1);
  k_film_part<<<dim3(8, 4, 8), 256, 0, stream>>>(cond, f2w, part);
  k_film_comb<<<dim3(8, 4), 256, 0, stream>>>(part, f2b_, ss2);

  k_rmsfilm<<<8192, 256, 0, stream>>>(x, n1w, ss1, h);

  // fused QKV: [8192,1024] @ [3072,1024]^T ; V stored transposed per batch
  k_gemm<256, EQKV, u16><<<dim3(12, 32, 1), 512, 0, stream>>>(
      h, qkvT, Q, qb, kb, vb, nullptr, Vt, 1.0f, 3072, 1024, 0, 0, 0);

  // S = Q @ K^T * D^-0.5 (batched)
  k_gemm<256, ES, u16><<<dim3(8, 8, 4), 512, 0, stream>>>(
      Q, Kb, S, nullptr, nullptr, nullptr, nullptr, nullptr, 0.03125f,
      2048, 1024, N * D, N * D, N * N);
  k_softmax<<<8192, 256, 0, stream>>>(S);

  // AO = P @ V (batched; B-operand = Vt[d][n])
  k_gemm<128, 0, u16><<<dim3(8, 8, 4), 512, 0, stream>>>(
      S, Vt, AO, nullptr, nullptr, nullptr, nullptr, nullptr, 1.0f,
      1024, 2048, N * N, D * N, N * D);

  // x1 = x + AO @ proj^T + pb
  k_gemm<128, EB | ER, float><<<dim3(8, 32, 1), 512, 0, stream>>>(
      AO, pT, x1, pb, nullptr, nullptr, x, nullptr, 1.0f, 1024, 1024, 0, 0, 0);

  k_rmsfilm<<<8192, 256, 0, stream>>>(x1, n2w, ss2, h);

  // h1 = gelu(h @ w1 + b1)
  k_gemm<256, EB | EG, u16><<<dim3(16, 32, 1), 512, 0, stream>>>(
      h, w1T, h1, b1, nullptr, nullptr, nullptr, nullptr, 1.0f, 4096, 1024, 0, 0, 0);

  // out = x1 + h1 @ w2 + b2
  k_gemm<128, EB | ER, float><<<dim3(8, 32, 1), 512, 0, stream>>>(
      h1, w2T, out, b2, nullptr, nullptr, x1, nullptr, 1.0f, 1024, 4096, 0, 0, 0);
}

// Round 4
// 435.201 us; speedup vs baseline: 1.5261x; 1.5261x over previous
//
#include <hip/hip_runtime.h>
#include <math.h>

typedef unsigned short u16;
typedef __bf16 bf16;
typedef bf16 bf16x8 __attribute__((ext_vector_type(8)));
typedef float f32x4 __attribute__((ext_vector_type(4)));

#define DEV __device__ __forceinline__
#define MFMA(a, b, c) __builtin_amdgcn_mfma_f32_16x16x32_bf16(a, b, c, 0, 0, 0)

DEV u16 f2b(float f) {
  unsigned u = __builtin_bit_cast(unsigned, f);
  u += 0x7fffu + ((u >> 16) & 1u);
  return (u16)(u >> 16);
}
DEV float b2f(u16 h) {
  unsigned u = ((unsigned)h) << 16;
  return __builtin_bit_cast(float, u);
}
DEV float gelu_f(float x) { return 0.5f * x * (1.0f + erff(x * 0.70710678118654752f)); }

DEV void gl2lds16(const void* g, void* l) {
  __builtin_amdgcn_global_load_lds(
      (const __attribute__((address_space(1))) unsigned int*)g,
      (__attribute__((address_space(3))) unsigned int*)l, 16, 0, 0);
}

// ---------------- weight transpose + fp32->bf16 ----------------
__global__ void k_transpose_cvt(const float* __restrict__ src, u16* __restrict__ dst,
                                int R, int C) {
  __shared__ float tile[32][33];
  const int c0 = blockIdx.x * 32, r0 = blockIdx.y * 32;
  const int tx = threadIdx.x, ty = threadIdx.y;  // 32 x 8
#pragma unroll
  for (int i = 0; i < 32; i += 8)
    tile[ty + i][tx] = src[(long)(r0 + ty + i) * C + c0 + tx];
  __syncthreads();
#pragma unroll
  for (int i = 0; i < 32; i += 8)
    dst[(long)(c0 + ty + i) * R + r0 + tx] = f2b(tile[tx][ty + i]);
}

// ---------------- FiLM ss = cond @ fw + fb, split-K ----------------
__global__ __launch_bounds__(256) void k_film_part(const float* __restrict__ cond,
                                                   const float* __restrict__ fw,
                                                   float* __restrict__ part) {
  const int j = blockIdx.x * 256 + threadIdx.x;
  const int b = blockIdx.y;
  const int kz = blockIdx.z;
  const float* cp = cond + b * 1024 + kz * 128;
  const float* wp = fw + (long)kz * 128 * 2048 + j;
  float acc = 0.0f;
#pragma unroll 4
  for (int d = 0; d < 128; ++d) acc = fmaf(cp[d], wp[(long)d * 2048], acc);
  part[((kz * 4 + b) << 11) + j] = acc;
}
__global__ __launch_bounds__(256) void k_film_comb(const float* __restrict__ part,
                                                   const float* __restrict__ fb,
                                                   float* __restrict__ ss) {
  const int j = blockIdx.x * 256 + threadIdx.x;
  const int b = blockIdx.y;
  float a = fb[j];
#pragma unroll
  for (int kz = 0; kz < 8; ++kz) a += part[((kz * 4 + b) << 11) + j];
  ss[b * 2048 + j] = a;
}

// ---------------- fused RMSNorm + FiLM, fp32 in -> bf16 out ----------------
__global__ __launch_bounds__(256) void k_rmsfilm(const float* __restrict__ x,
                                                 const float* __restrict__ nw,
                                                 const float* __restrict__ ss,
                                                 u16* __restrict__ h) {
  const int row = blockIdx.x;
  const int b = row >> 11;
  const int t = threadIdx.x;
  const float4 v = ((const float4*)(x + (long)row * 1024))[t];
  float s = v.x * v.x + v.y * v.y + v.z * v.z + v.w * v.w;
#pragma unroll
  for (int off = 32; off; off >>= 1) s += __shfl_xor(s, off);
  __shared__ float red[4];
  const int wv = t >> 6, lane = t & 63;
  if (lane == 0) red[wv] = s;
  __syncthreads();
  const float tot = red[0] + red[1] + red[2] + red[3];
  const float rn = rsqrtf(tot * (1.0f / 1024.0f) + 1e-6f);
  const float4 w4 = ((const float4*)nw)[t];
  const float4 sc = ((const float4*)(ss + b * 2048))[t];
  const float4 sh = ((const float4*)(ss + b * 2048 + 1024))[t];
  ushort4 o;
  o.x = f2b(v.x * rn * w4.x * (1.0f + sc.x) + sh.x);
  o.y = f2b(v.y * rn * w4.y * (1.0f + sc.y) + sh.y);
  o.z = f2b(v.z * rn * w4.z * (1.0f + sc.z) + sh.z);
  o.w = f2b(v.w * rn * w4.w * (1.0f + sc.w) + sh.w);
  ((ushort4*)(h + (long)row * 1024))[t] = o;
}

// ---------------- row softmax over 2048 bf16, in place ----------------
__global__ __launch_bounds__(256) void k_softmax(u16* __restrict__ S) {
  u16* p = S + ((long)blockIdx.x << 11);
  const int t = threadIdx.x;
  ushort4 u0 = ((ushort4*)p)[2 * t], u1 = ((ushort4*)p)[2 * t + 1];
  float f[8] = {b2f(u0.x), b2f(u0.y), b2f(u0.z), b2f(u0.w),
                b2f(u1.x), b2f(u1.y), b2f(u1.z), b2f(u1.w)};
  float m = f[0];
#pragma unroll
  for (int i = 1; i < 8; ++i) m = fmaxf(m, f[i]);
#pragma unroll
  for (int off = 32; off; off >>= 1) m = fmaxf(m, __shfl_xor(m, off));
  __shared__ float red[4];
  const int wv = t >> 6, lane = t & 63;
  if (lane == 0) red[wv] = m;
  __syncthreads();
  m = fmaxf(fmaxf(red[0], red[1]), fmaxf(red[2], red[3]));
  float s = 0.0f;
#pragma unroll
  for (int i = 0; i < 8; ++i) {
    f[i] = __expf(f[i] - m);
    s += f[i];
  }
#pragma unroll
  for (int off = 32; off; off >>= 1) s += __shfl_xor(s, off);
  __syncthreads();
  if (lane == 0) red[wv] = s;
  __syncthreads();
  const float inv = 1.0f / (red[0] + red[1] + red[2] + red[3]);
  ushort4 o0, o1;
  o0.x = f2b(f[0] * inv); o0.y = f2b(f[1] * inv);
  o0.z = f2b(f[2] * inv); o0.w = f2b(f[3] * inv);
  o1.x = f2b(f[4] * inv); o1.y = f2b(f[5] * inv);
  o1.z = f2b(f[6] * inv); o1.w = f2b(f[7] * inv);
  ((ushort4*)p)[2 * t] = o0;
  ((ushort4*)p)[2 * t + 1] = o1;
}

// ---------------- m97-form bf16 MFMA GEMM, 128x128 tile, BK=64 ----------------
// C = A[M,K] @ Bt[N,K]^T. 4 waves (2x2), single-buffered LDS, 2 syncs per
// K-step. LDS rows are 128B (BK=64): XOR-swizzle slot^=(row&7) applied on the
// pre-swizzled global source (linear global_load_lds dest) and on ds_read.
enum { EB = 1, ES = 2, EG = 4, ER = 8, EQKV = 16 };

template <int EPI, typename OutT>
__global__ __launch_bounds__(256, 2) void k_gemm(
    const u16* __restrict__ A, const u16* __restrict__ B, OutT* __restrict__ C,
    const float* __restrict__ bias, const float* __restrict__ bias2,
    const float* __restrict__ bias3, const float* __restrict__ resid,
    u16* __restrict__ Vt, float scale, int N, int K, long sAb, long sBb, long sCb) {
  __shared__ u16 As[128 * 64];
  __shared__ u16 Bs[128 * 64];
  const int tid = threadIdx.x, lane = tid & 63, wv = tid >> 6;
  const int wr = wv >> 1, wc = wv & 1;
  const int r = lane & 15, q = lane >> 4;

  // XCD-aware bijective swizzle (all grids have gridDim.x*gridDim.y % 8 == 0)
  int flat = blockIdx.y * gridDim.x + blockIdx.x;
  const int nxy = gridDim.x * gridDim.y;
  flat = (flat & 7) * (nxy >> 3) + (flat >> 3);
  const int bx = flat % gridDim.x, by = flat / gridDim.x;

  const long bm = (long)by * 128, bn = (long)bx * 128;
  const u16* Ab = A + (long)blockIdx.z * sAb + bm * K;
  const u16* Bb = B + (long)blockIdx.z * sBb + bn * K;

  // staging: chunk c in 0..1023 covers row=c>>3, 16B-slot=c&7 (linear LDS dest);
  // global source slot is pre-swizzled so LDS holds slot^(row&7).
  f32x4 acc[4][4] = {};

  for (int k0 = 0; k0 < K; k0 += 64) {
#pragma unroll
    for (int i = 0; i < 4; ++i) {
      const int c = i * 256 + tid;
      const int row = c >> 3, sp = c & 7;
      const long g = (long)row * K + k0 + ((sp ^ (row & 7)) << 3);
      gl2lds16(Ab + g, As + c * 8);
      gl2lds16(Bb + g, Bs + c * 8);
    }
    __syncthreads();
    bf16x8 a[8], b[8];
#pragma unroll
    for (int kh = 0; kh < 2; ++kh) {
#pragma unroll
      for (int i = 0; i < 4; ++i) {
        const int ar = wr * 64 + i * 16 + r;
        const int br = wc * 64 + i * 16 + r;
        a[kh * 4 + i] = *(const bf16x8*)&As[ar * 64 + ((kh * 4 + q) ^ (ar & 7)) * 8];
        b[kh * 4 + i] = *(const bf16x8*)&Bs[br * 64 + ((kh * 4 + q) ^ (br & 7)) * 8];
      }
    }
#pragma unroll
    for (int kh = 0; kh < 2; ++kh)
#pragma unroll
      for (int mi = 0; mi < 4; ++mi)
#pragma unroll
        for (int ni = 0; ni < 4; ++ni)
          acc[mi][ni] = MFMA(a[kh * 4 + mi], b[kh * 4 + ni], acc[mi][ni]);
    __syncthreads();
  }

  // ---------------- epilogue ----------------
  const long cb = (long)blockIdx.z * sCb;
#pragma unroll
  for (int ni = 0; ni < 4; ++ni) {
    const long col = bn + wc * 64 + ni * 16 + r;
    float bv = 0.0f;
    int reg = 0, c = (int)col;
    if constexpr ((EPI & EB) != 0) bv = bias[col];
    if constexpr ((EPI & EQKV) != 0) {
      reg = (int)(col >> 10);
      c = (int)col & 1023;
      bv = (reg == 0) ? bias[c] : (reg == 1) ? bias2[c] : bias3[c];
    }
#pragma unroll
    for (int mi = 0; mi < 4; ++mi) {
#pragma unroll
      for (int j = 0; j < 4; ++j) {
        const long row = bm + wr * 64 + mi * 16 + q * 4 + j;
        float v = acc[mi][ni][j];
        if constexpr ((EPI & ES) != 0) v *= scale;
        if constexpr ((EPI & (EB | EQKV)) != 0) v += bv;
        if constexpr ((EPI & EG) != 0) v = gelu_f(v);
        if constexpr ((EPI & ER) != 0) v += resid[row * N + col];
        if constexpr ((EPI & EQKV) != 0) {
          if (reg < 2)
            ((u16*)C)[(long)reg * 8388608 + row * 1024 + c] = f2b(v);
          else
            Vt[((row >> 11) << 21) + ((long)c << 11) + (row & 2047)] = f2b(v);
        } else if constexpr (sizeof(OutT) == 4) {
          C[cb + row * N + col] = v;
        } else {
          C[cb + row * N + col] = f2b(v);
        }
      }
    }
  }
}

extern "C" void kernel_launch(void* const* d_in, const int* in_sizes, int n_in,
                              void* d_out, int out_size, void* d_ws, size_t ws_size,
                              hipStream_t stream) {
  const float* x    = (const float*)d_in[0];
  const float* cond = (const float*)d_in[1];
  const float* n1w  = (const float*)d_in[2];
  const float* f1w  = (const float*)d_in[3];
  const float* f1b  = (const float*)d_in[4];
  const float* qw   = (const float*)d_in[5];
  const float* qb   = (const float*)d_in[6];
  const float* kw   = (const float*)d_in[7];
  const float* kb   = (const float*)d_in[8];
  const float* vw   = (const float*)d_in[9];
  const float* vb   = (const float*)d_in[10];
  const float* pw   = (const float*)d_in[11];
  const float* pb   = (const float*)d_in[12];
  const float* n2w  = (const float*)d_in[13];
  const float* f2w  = (const float*)d_in[14];
  const float* f2b_ = (const float*)d_in[15];
  const float* w1   = (const float*)d_in[16];
  const float* b1   = (const float*)d_in[17];
  const float* w2   = (const float*)d_in[18];
  const float* b2   = (const float*)d_in[19];
  float* out = (float*)d_out;

  char* ws = (char*)d_ws;
  size_t o = 0;
  auto alloc = [&](size_t bytes) {
    size_t ret = o;
    o += (bytes + 255) & ~(size_t)255;
    return ret;
  };
  const long N = 2048, D = 1024, H = 4096;

  u16* qkvT = (u16*)(ws + alloc(3 * D * D * 2));  // [3072][1024] = qT;kT;vT
  u16* pT   = (u16*)(ws + alloc(D * D * 2));
  u16* w1T  = (u16*)(ws + alloc(D * H * 2));
  u16* w2T  = (u16*)(ws + alloc(D * H * 2));
  float* ss1  = (float*)(ws + alloc(4 * 2 * D * 4));
  float* ss2  = (float*)(ws + alloc(4 * 2 * D * 4));
  float* part = (float*)(ws + alloc(8 * 4 * 2 * D * 4));
  u16* h    = (u16*)(ws + alloc(4 * N * D * 2));    // 16 MB
  float* x1 = (float*)(ws + alloc(4 * N * D * 4));  // 32 MB
  u16* AO   = (u16*)(ws + alloc(4 * N * D * 2));    // 16 MB
  const size_t big = o;  // alias region
  u16* Q    = (u16*)(ws + alloc(4 * N * D * 2));    // Q and Kb must stay adjacent
  u16* Kb   = (u16*)(ws + alloc(4 * N * D * 2));
  u16* Vt   = (u16*)(ws + alloc(4 * N * D * 2));
  u16* S    = (u16*)(ws + alloc(4 * N * N * 2));    // 32 MB
  u16* h1   = (u16*)(ws + big);                     // 64 MB, aliases Q..S
  (void)ws_size; (void)in_sizes; (void)n_in; (void)out_size; (void)Kb;

  dim3 tb(32, 8);
  k_transpose_cvt<<<dim3(32, 32), tb, 0, stream>>>(qw, qkvT, 1024, 1024);
  k_transpose_cvt<<<dim3(32, 32), tb, 0, stream>>>(kw, qkvT + 1024 * 1024, 1024, 1024);
  k_transpose_cvt<<<dim3(32, 32), tb, 0, stream>>>(vw, qkvT + 2 * 1024 * 1024, 1024, 1024);
  k_transpose_cvt<<<dim3(32, 32), tb, 0, stream>>>(pw, pT, 1024, 1024);
  k_transpose_cvt<<<dim3(128, 32), tb, 0, stream>>>(w1, w1T, 1024, 4096);
  k_transpose_cvt<<<dim3(32, 128), tb, 0, stream>>>(w2, w2T, 4096, 1024);

  k_film_part<<<dim3(8, 4, 8), 256, 0, stream>>>(cond, f1w, part);
  k_film_comb<<<dim3(8, 4), 256, 0, stream>>>(part, f1b, ss1);
  k_film_part<<<dim3(8, 4, 8), 256, 0, stream>>>(cond, f2w, part);
  k_film_comb<<<dim3(8, 4), 256, 0, stream>>>(part, f2b_, ss2);

  k_rmsfilm<<<8192, 256, 0, stream>>>(x, n1w, ss1, h);

  // fused QKV: [8192,1024] @ [3072,1024]^T ; V stored transposed per batch
  k_gemm<EQKV, u16><<<dim3(24, 64, 1), 256, 0, stream>>>(
      h, qkvT, Q, qb, kb, vb, nullptr, Vt, 1.0f, 3072, 1024, 0, 0, 0);

  // S = Q @ K^T * D^-0.5 (batched)
  k_gemm<ES, u16><<<dim3(16, 16, 4), 256, 0, stream>>>(
      Q, Kb, S, nullptr, nullptr, nullptr, nullptr, nullptr, 0.03125f,
      2048, 1024, N * D, N * D, N * N);
  k_softmax<<<8192, 256, 0, stream>>>(S);

  // AO = P @ V (batched; B-operand = Vt[d][n])
  k_gemm<0, u16><<<dim3(8, 16, 4), 256, 0, stream>>>(
      S, Vt, AO, nullptr, nullptr, nullptr, nullptr, nullptr, 1.0f,
      1024, 2048, N * N, D * N, N * D);

  // x1 = x + AO @ proj^T + pb
  k_gemm<EB | ER, float><<<dim3(8, 64, 1), 256, 0, stream>>>(
      AO, pT, x1, pb, nullptr, nullptr, x, nullptr, 1.0f, 1024, 1024, 0, 0, 0);

  k_rmsfilm<<<8192, 256, 0, stream>>>(x1, n2w, ss2, h);

  // h1 = gelu(h @ w1 + b1)
  k_gemm<EB | EG, u16><<<dim3(32, 64, 1), 256, 0, stream>>>(
      h, w1T, h1, b1, nullptr, nullptr, nullptr, nullptr, 1.0f, 4096, 1024, 0, 0, 0);

  // out = x1 + h1 @ w2 + b2
  k_gemm<EB | ER, float><<<dim3(8, 64, 1), 256, 0, stream>>>(
      h1, w2T, out, b2, nullptr, nullptr, x1, nullptr, 1.0f, 1024, 4096, 0, 0, 0);
}

// Round 5
// 394.677 us; speedup vs baseline: 1.6828x; 1.1027x over previous
//
#include <hip/hip_runtime.h>
#include <math.h>

typedef unsigned short u16;
typedef __bf16 bf16;
typedef bf16 bf16x8 __attribute__((ext_vector_type(8)));
typedef float f32x4 __attribute__((ext_vector_type(4)));

#define DEV __device__ __forceinline__
#define MFMA(a, b, c) __builtin_amdgcn_mfma_f32_16x16x32_bf16(a, b, c, 0, 0, 0)

DEV u16 f2b(float f) {
  unsigned u = __builtin_bit_cast(unsigned, f);
  u += 0x7fffu + ((u >> 16) & 1u);
  return (u16)(u >> 16);
}
DEV float b2f(u16 h) {
  unsigned u = ((unsigned)h) << 16;
  return __builtin_bit_cast(float, u);
}
// gelu(x) ~= x * sigmoid(1.5957691x + 0.0713548x^3)  (tanh-form, |err|<=0.003)
DEV float gelu_f(float x) {
  float e = __expf(x * (-1.5957691216f - 0.07135481283f * x * x));
  return x / (1.0f + e);
}

DEV void gl2lds16(const void* g, void* l) {
  __builtin_amdgcn_global_load_lds(
      (const __attribute__((address_space(1))) unsigned int*)g,
      (__attribute__((address_space(3))) unsigned int*)l, 16, 0, 0);
}

// ---------------- fused 6-matrix transpose + fp32->bf16 ----------------
struct TDesc { const float* src; u16* dst; int R, C, t0, tx; };
struct T6 { TDesc d[6]; };

__global__ void k_transpose6(T6 td) {
  __shared__ float tile[32][33];
  const int id = blockIdx.x;
  TDesc d = td.d[0];
#pragma unroll
  for (int k = 1; k < 6; ++k)
    if (id >= td.d[k].t0) d = td.d[k];
  const int local = id - d.t0;
  const int c0 = (local % d.tx) * 32, r0 = (local / d.tx) * 32;
  const int tx = threadIdx.x, ty = threadIdx.y;  // 32 x 8
#pragma unroll
  for (int i = 0; i < 32; i += 8)
    tile[ty + i][tx] = d.src[(long)(r0 + ty + i) * d.C + c0 + tx];
  __syncthreads();
#pragma unroll
  for (int i = 0; i < 32; i += 8)
    d.dst[(long)(c0 + ty + i) * d.R + r0 + tx] = f2b(tile[tx][ty + i]);
}

// ---------------- FiLM ss = cond @ fw + fb, split-K, both films ----------------
__global__ __launch_bounds__(256) void k_film_part(const float* __restrict__ cond,
                                                   const float* __restrict__ f1w,
                                                   const float* __restrict__ f2w,
                                                   float* __restrict__ part) {
  const int j = blockIdx.x * 256 + threadIdx.x;  // 0..2047
  const int b = blockIdx.y;                      // 0..3
  const int z = blockIdx.z;                      // 0..15
  const int kz = z & 7;
  const float* fw = (z < 8) ? f1w : f2w;
  const float* cp = cond + b * 1024 + kz * 128;
  const float* wp = fw + (long)kz * 128 * 2048 + j;
  float acc = 0.0f;
#pragma unroll 4
  for (int d = 0; d < 128; ++d) acc = fmaf(cp[d], wp[(long)d * 2048], acc);
  part[((z * 4 + b) << 11) + j] = acc;
}
__global__ __launch_bounds__(256) void k_film_comb(const float* __restrict__ part,
                                                   const float* __restrict__ f1b,
                                                   const float* __restrict__ f2b_,
                                                   float* __restrict__ ss) {
  const int j = blockIdx.x * 256 + threadIdx.x;
  const int b = blockIdx.y & 3, f = blockIdx.y >> 2;
  float a = (f ? f2b_ : f1b)[j];
#pragma unroll
  for (int kz = 0; kz < 8; ++kz) a += part[(((f * 8 + kz) * 4 + b) << 11) + j];
  ss[((f * 4 + b) << 11) + j] = a;
}

// ---------------- fused RMSNorm + FiLM -> bf16 (fp32 or bf16 input) ----------------
template <typename InT>
__global__ __launch_bounds__(256) void k_rmsfilm(const InT* __restrict__ x,
                                                 const float* __restrict__ nw,
                                                 const float* __restrict__ ss,
                                                 u16* __restrict__ h) {
  const int row = blockIdx.x;
  const int b = row >> 11;
  const int t = threadIdx.x;
  float4 v;
  if constexpr (sizeof(InT) == 4) {
    v = ((const float4*)(x + (long)row * 1024))[t];
  } else {
    ushort4 u = ((const ushort4*)(x + (long)row * 1024))[t];
    v = make_float4(b2f(u.x), b2f(u.y), b2f(u.z), b2f(u.w));
  }
  float s = v.x * v.x + v.y * v.y + v.z * v.z + v.w * v.w;
#pragma unroll
  for (int off = 32; off; off >>= 1) s += __shfl_xor(s, off);
  __shared__ float red[4];
  const int wv = t >> 6, lane = t & 63;
  if (lane == 0) red[wv] = s;
  __syncthreads();
  const float tot = red[0] + red[1] + red[2] + red[3];
  const float rn = rsqrtf(tot * (1.0f / 1024.0f) + 1e-6f);
  const float4 w4 = ((const float4*)nw)[t];
  const float4 sc = ((const float4*)(ss + b * 2048))[t];
  const float4 sh = ((const float4*)(ss + b * 2048 + 1024))[t];
  ushort4 o;
  o.x = f2b(v.x * rn * w4.x * (1.0f + sc.x) + sh.x);
  o.y = f2b(v.y * rn * w4.y * (1.0f + sc.y) + sh.y);
  o.z = f2b(v.z * rn * w4.z * (1.0f + sc.z) + sh.z);
  o.w = f2b(v.w * rn * w4.w * (1.0f + sc.w) + sh.w);
  ((ushort4*)(h + (long)row * 1024))[t] = o;
}

// ---------------- row softmax over 2048 bf16, in place ----------------
__global__ __launch_bounds__(256) void k_softmax(u16* __restrict__ S) {
  u16* p = S + ((long)blockIdx.x << 11);
  const int t = threadIdx.x;
  ushort4 u0 = ((ushort4*)p)[2 * t], u1 = ((ushort4*)p)[2 * t + 1];
  float f[8] = {b2f(u0.x), b2f(u0.y), b2f(u0.z), b2f(u0.w),
                b2f(u1.x), b2f(u1.y), b2f(u1.z), b2f(u1.w)};
  float m = f[0];
#pragma unroll
  for (int i = 1; i < 8; ++i) m = fmaxf(m, f[i]);
#pragma unroll
  for (int off = 32; off; off >>= 1) m = fmaxf(m, __shfl_xor(m, off));
  __shared__ float red[4];
  const int wv = t >> 6, lane = t & 63;
  if (lane == 0) red[wv] = m;
  __syncthreads();
  m = fmaxf(fmaxf(red[0], red[1]), fmaxf(red[2], red[3]));
  float s = 0.0f;
#pragma unroll
  for (int i = 0; i < 8; ++i) {
    f[i] = __expf(f[i] - m);
    s += f[i];
  }
#pragma unroll
  for (int off = 32; off; off >>= 1) s += __shfl_xor(s, off);
  __syncthreads();
  if (lane == 0) red[wv] = s;
  __syncthreads();
  const float inv = 1.0f / (red[0] + red[1] + red[2] + red[3]);
  ushort4 o0, o1;
  o0.x = f2b(f[0] * inv); o0.y = f2b(f[1] * inv);
  o0.z = f2b(f[2] * inv); o0.w = f2b(f[3] * inv);
  o1.x = f2b(f[4] * inv); o1.y = f2b(f[5] * inv);
  o1.z = f2b(f[6] * inv); o1.w = f2b(f[7] * inv);
  ((ushort4*)p)[2 * t] = o0;
  ((ushort4*)p)[2 * t + 1] = o1;
}

// ---------------- m97-form bf16 MFMA GEMM, 128x128 tile, BK=64 ----------------
// C = A[M,K] @ Bt[N,K]^T. 4 waves (2x2), single-buffered LDS, 2 syncs per
// K-step. LDS rows are 128B (BK=64): XOR-swizzle slot^=(row&7) applied on the
// pre-swizzled global source (linear global_load_lds dest) and on ds_read.
enum { EB = 1, ES = 2, EG = 4, ER = 8, EQKV = 16, ERB = 32 };

template <int EPI, typename OutT>
__global__ __launch_bounds__(256, 2) void k_gemm(
    const u16* __restrict__ A, const u16* __restrict__ B, OutT* __restrict__ C,
    const float* __restrict__ bias, const float* __restrict__ bias2,
    const float* __restrict__ bias3, const float* __restrict__ resid,
    u16* __restrict__ Vt, float scale, int N, int K, long sAb, long sBb, long sCb) {
  __shared__ u16 As[128 * 64];
  __shared__ u16 Bs[128 * 64];
  const int tid = threadIdx.x, lane = tid & 63, wv = tid >> 6;
  const int wr = wv >> 1, wc = wv & 1;
  const int r = lane & 15, q = lane >> 4;

  // XCD-aware bijective swizzle (all grids have gridDim.x*gridDim.y % 8 == 0)
  int flat = blockIdx.y * gridDim.x + blockIdx.x;
  const int nxy = gridDim.x * gridDim.y;
  flat = (flat & 7) * (nxy >> 3) + (flat >> 3);
  const int bx = flat % gridDim.x, by = flat / gridDim.x;

  const long bm = (long)by * 128, bn = (long)bx * 128;
  const u16* Ab = A + (long)blockIdx.z * sAb + bm * K;
  const u16* Bb = B + (long)blockIdx.z * sBb + bn * K;

  // staging: chunk c in 0..1023 covers row=c>>3, 16B-slot=c&7 (linear LDS dest);
  // global source slot is pre-swizzled so LDS holds slot^(row&7).
  f32x4 acc[4][4] = {};

  for (int k0 = 0; k0 < K; k0 += 64) {
#pragma unroll
    for (int i = 0; i < 4; ++i) {
      const int c = i * 256 + tid;
      const int row = c >> 3, sp = c & 7;
      const long g = (long)row * K + k0 + ((sp ^ (row & 7)) << 3);
      gl2lds16(Ab + g, As + c * 8);
      gl2lds16(Bb + g, Bs + c * 8);
    }
    __syncthreads();
    bf16x8 a[8], b[8];
#pragma unroll
    for (int kh = 0; kh < 2; ++kh) {
#pragma unroll
      for (int i = 0; i < 4; ++i) {
        const int ar = wr * 64 + i * 16 + r;
        const int br = wc * 64 + i * 16 + r;
        a[kh * 4 + i] = *(const bf16x8*)&As[ar * 64 + ((kh * 4 + q) ^ (ar & 7)) * 8];
        b[kh * 4 + i] = *(const bf16x8*)&Bs[br * 64 + ((kh * 4 + q) ^ (br & 7)) * 8];
      }
    }
#pragma unroll
    for (int kh = 0; kh < 2; ++kh)
#pragma unroll
      for (int mi = 0; mi < 4; ++mi)
#pragma unroll
        for (int ni = 0; ni < 4; ++ni)
          acc[mi][ni] = MFMA(a[kh * 4 + mi], b[kh * 4 + ni], acc[mi][ni]);
    __syncthreads();
  }

  // ---------------- epilogue ----------------
  const long cb = (long)blockIdx.z * sCb;
#pragma unroll
  for (int ni = 0; ni < 4; ++ni) {
    const long col = bn + wc * 64 + ni * 16 + r;
    float bv = 0.0f;
    int reg = 0, c = (int)col;
    if constexpr ((EPI & EB) != 0) bv = bias[col];
    if constexpr ((EPI & EQKV) != 0) {
      reg = (int)(col >> 10);
      c = (int)col & 1023;
      bv = (reg == 0) ? bias[c] : (reg == 1) ? bias2[c] : bias3[c];
    }
#pragma unroll
    for (int mi = 0; mi < 4; ++mi) {
#pragma unroll
      for (int j = 0; j < 4; ++j) {
        const long row = bm + wr * 64 + mi * 16 + q * 4 + j;
        float v = acc[mi][ni][j];
        if constexpr ((EPI & ES) != 0) v *= scale;
        if constexpr ((EPI & (EB | EQKV)) != 0) v += bv;
        if constexpr ((EPI & EG) != 0) v = gelu_f(v);
        if constexpr ((EPI & ER) != 0) v += resid[row * N + col];
        if constexpr ((EPI & ERB) != 0) v += b2f(((const u16*)resid)[row * N + col]);
        if constexpr ((EPI & EQKV) != 0) {
          if (reg < 2)
            ((u16*)C)[(long)reg * 8388608 + row * 1024 + c] = f2b(v);
          else
            Vt[((row >> 11) << 21) + ((long)c << 11) + (row & 2047)] = f2b(v);
        } else if constexpr (sizeof(OutT) == 4) {
          C[cb + row * N + col] = v;
        } else {
          C[cb + row * N + col] = f2b(v);
        }
      }
    }
  }
}

extern "C" void kernel_launch(void* const* d_in, const int* in_sizes, int n_in,
                              void* d_out, int out_size, void* d_ws, size_t ws_size,
                              hipStream_t stream) {
  const float* x    = (const float*)d_in[0];
  const float* cond = (const float*)d_in[1];
  const float* n1w  = (const float*)d_in[2];
  const float* f1w  = (const float*)d_in[3];
  const float* f1b  = (const float*)d_in[4];
  const float* qw   = (const float*)d_in[5];
  const float* qb   = (const float*)d_in[6];
  const float* kw   = (const float*)d_in[7];
  const float* kb   = (const float*)d_in[8];
  const float* vw   = (const float*)d_in[9];
  const float* vb   = (const float*)d_in[10];
  const float* pw   = (const float*)d_in[11];
  const float* pb   = (const float*)d_in[12];
  const float* n2w  = (const float*)d_in[13];
  const float* f2w  = (const float*)d_in[14];
  const float* f2b_ = (const float*)d_in[15];
  const float* w1   = (const float*)d_in[16];
  const float* b1   = (const float*)d_in[17];
  const float* w2   = (const float*)d_in[18];
  const float* b2   = (const float*)d_in[19];
  float* out = (float*)d_out;

  char* ws = (char*)d_ws;
  size_t o = 0;
  auto alloc = [&](size_t bytes) {
    size_t ret = o;
    o += (bytes + 255) & ~(size_t)255;
    return ret;
  };
  const long N = 2048, D = 1024, H = 4096;

  u16* qkvT = (u16*)(ws + alloc(3 * D * D * 2));  // [3072][1024] = qT;kT;vT
  u16* pT   = (u16*)(ws + alloc(D * D * 2));
  u16* w1T  = (u16*)(ws + alloc(D * H * 2));
  u16* w2T  = (u16*)(ws + alloc(D * H * 2));
  float* ss   = (float*)(ws + alloc(2 * 4 * 2 * D * 4));   // [2][4][2048]
  float* part = (float*)(ws + alloc(16 * 4 * 2 * D * 4));  // [16][4][2048]
  u16* h    = (u16*)(ws + alloc(4 * N * D * 2));    // 16 MB
  u16* x1b  = (u16*)(ws + alloc(4 * N * D * 2));    // 16 MB (bf16 residual)
  u16* AO   = (u16*)(ws + alloc(4 * N * D * 2));    // 16 MB
  const size_t big = o;  // alias region
  u16* Q    = (u16*)(ws + alloc(4 * N * D * 2));    // Q and Kb must stay adjacent
  u16* Kb   = (u16*)(ws + alloc(4 * N * D * 2));
  u16* Vt   = (u16*)(ws + alloc(4 * N * D * 2));
  u16* S    = (u16*)(ws + alloc(4 * N * N * 2));    // 32 MB
  u16* h1   = (u16*)(ws + big);                     // 64 MB, aliases Q..S
  (void)ws_size; (void)in_sizes; (void)n_in; (void)out_size; (void)Kb;

  // fused weight transposes (q,k,v,p,w1,w2)
  T6 td;
  td.d[0] = {qw, qkvT,                1024, 1024,    0,  32};
  td.d[1] = {kw, qkvT + 1024 * 1024,  1024, 1024, 1024,  32};
  td.d[2] = {vw, qkvT + 2048 * 1024,  1024, 1024, 2048,  32};
  td.d[3] = {pw, pT,                  1024, 1024, 3072,  32};
  td.d[4] = {w1, w1T,                 1024, 4096, 4096, 128};
  td.d[5] = {w2, w2T,                 4096, 1024, 8192,  32};
  k_transpose6<<<12288, dim3(32, 8), 0, stream>>>(td);

  k_film_part<<<dim3(8, 4, 16), 256, 0, stream>>>(cond, f1w, f2w, part);
  k_film_comb<<<dim3(8, 8), 256, 0, stream>>>(part, f1b, f2b_, ss);

  k_rmsfilm<float><<<8192, 256, 0, stream>>>(x, n1w, ss, h);

  // fused QKV: [8192,1024] @ [3072,1024]^T ; V stored transposed per batch
  k_gemm<EQKV, u16><<<dim3(24, 64, 1), 256, 0, stream>>>(
      h, qkvT, Q, qb, kb, vb, nullptr, Vt, 1.0f, 3072, 1024, 0, 0, 0);

  // S = Q @ K^T * D^-0.5 (batched)
  k_gemm<ES, u16><<<dim3(16, 16, 4), 256, 0, stream>>>(
      Q, Kb, S, nullptr, nullptr, nullptr, nullptr, nullptr, 0.03125f,
      2048, 1024, N * D, N * D, N * N);
  k_softmax<<<8192, 256, 0, stream>>>(S);

  // AO = P @ V (batched; B-operand = Vt[d][n])
  k_gemm<0, u16><<<dim3(8, 16, 4), 256, 0, stream>>>(
      S, Vt, AO, nullptr, nullptr, nullptr, nullptr, nullptr, 1.0f,
      1024, 2048, N * N, D * N, N * D);

  // x1 = x + AO @ proj^T + pb   (stored bf16)
  k_gemm<EB | ER, u16><<<dim3(8, 64, 1), 256, 0, stream>>>(
      AO, pT, x1b, pb, nullptr, nullptr, x, nullptr, 1.0f, 1024, 1024, 0, 0, 0);

  k_rmsfilm<u16><<<8192, 256, 0, stream>>>(x1b, n2w, ss + 4 * 2048, h);

  // h1 = gelu(h @ w1 + b1)
  k_gemm<EB | EG, u16><<<dim3(32, 64, 1), 256, 0, stream>>>(
      h, w1T, h1, b1, nullptr, nullptr, nullptr, nullptr, 1.0f, 4096, 1024, 0, 0, 0);

  // out = x1 + h1 @ w2 + b2
  k_gemm<EB | ERB, float><<<dim3(8, 64, 1), 256, 0, stream>>>(
      h1, w2T, out, b2, nullptr, nullptr, (const float*)x1b, nullptr, 1.0f, 1024, 4096, 0, 0, 0);
}